// Round 1
// baseline (9341.467 us; speedup 1.0000x reference)
//
#include <hip/hip_runtime.h>

// Problem: B=64, T=512, I=256, H=512, C=128. LSTM forward (truncation is a
// forward no-op) + final linear projection. fp32 in/out; bf16 MFMA inside.
#define B_ 64
#define T_ 512
#define I_ 256
#define H_ 512
#define C_ 128
#define G4_ (4 * H_)          // 2048 gate rows
#define NWG 64                // one wg per 8 h-columns; 32 gate rows each
#define HS_ELEMS ((size_t)T_ * B_ * H_)          // bf16 h archive/broadcast
#define HS_BYTES (HS_ELEMS * 2)                  // 32 MB

typedef __bf16 bf16x8 __attribute__((ext_vector_type(8)));
typedef float f32x4 __attribute__((ext_vector_type(4)));

__device__ __forceinline__ bf16x8 cvt8(const float4 a, const float4 b) {
    bf16x8 r;
    r[0] = (__bf16)a.x; r[1] = (__bf16)a.y; r[2] = (__bf16)a.z; r[3] = (__bf16)a.w;
    r[4] = (__bf16)b.x; r[5] = (__bf16)b.y; r[6] = (__bf16)b.z; r[7] = (__bf16)b.w;
    return r;
}

__device__ __forceinline__ float sigm(float x) {
    return __frcp_rn(1.0f + __expf(-x));
}
__device__ __forceinline__ float tanh_(float x) {
    // 2*sigmoid(2x)-1; exact at +-inf, fine near 0 (abs err ~1e-7)
    return 2.0f * sigm(2.0f * x) - 1.0f;
}

// ---------------------------------------------------------------------------
// Recurrent kernel: 64 wgs x 512 threads (8 waves). wg p owns h columns
// [8p, 8p+8) i.e. gate rows {g*512 + 8p + k : g in 0..4, k in 0..8}.
// Wave w: MFMA output tile (m = w>>1 over b, n = w&1 over 16 gate cols).
// W_hh/W_ih B-fragments live in VGPRs for the whole kernel.
// Per-step sync: flag[p] counts completed steps (monotone, memset to 0).
// ---------------------------------------------------------------------------
__global__ void __launch_bounds__(512, 2)
lstm_kernel(const float* __restrict__ x, const float* __restrict__ W_ih,
            const float* __restrict__ W_hh, const float* __restrict__ b_ih,
            const float* __restrict__ b_hh, unsigned short* __restrict__ hs,
            int* __restrict__ flags)
{
    const int p    = blockIdx.x;          // 0..63
    const int tid  = threadIdx.x;
    const int w    = tid >> 6;            // wave 0..7
    const int lane = tid & 63;
    const int l15  = lane & 15;
    const int quad = lane >> 4;
    const int mt   = w >> 1;              // b-tile 0..3
    const int nt   = w & 1;               // gate-col tile 0..1
    const int arow = mt * 16 + l15;       // A-operand row (batch index b)

    __shared__ float gates_lds[64 * 33];  // [b][jl], pad 33 -> conflict-free

    // ---- stationary weight fragments (B operand: B[k][n], n = lane&15) ----
    const int jl = nt * 16 + l15;                         // 0..31 within slice
    const int J  = (jl >> 3) * H_ + p * 8 + (jl & 7);     // global gate row
    bf16x8 wh[16], wi[8];
#pragma unroll
    for (int kc = 0; kc < 16; ++kc) {
        const float* sp = W_hh + (size_t)J * H_ + kc * 32 + quad * 8;
        wh[kc] = cvt8(((const float4*)sp)[0], ((const float4*)sp)[1]);
    }
#pragma unroll
    for (int kc = 0; kc < 8; ++kc) {
        const float* sp = W_ih + (size_t)J * I_ + kc * 32 + quad * 8;
        wi[kc] = cvt8(((const float4*)sp)[0], ((const float4*)sp)[1]);
    }

    // ---- per-thread elementwise identity: b = lane, k = 8p + w ----
    float bias[4];
#pragma unroll
    for (int g = 0; g < 4; ++g) {
        int j2 = g * H_ + p * 8 + w;
        bias[g] = b_ih[j2] + b_hh[j2];
    }
    float c_state = 0.0f;

    for (int t = 0; t < T_; ++t) {
        // 1) prefetch + convert this step's x fragments (independent of peers)
        bf16x8 xf[8];
#pragma unroll
        for (int kc = 0; kc < 8; ++kc) {
            const float* xp = x + ((size_t)arow * T_ + t) * I_ + kc * 32 + quad * 8;
            xf[kc] = cvt8(((const float4*)xp)[0], ((const float4*)xp)[1]);
        }

        // 2) wait for all 64 producers to finish step t-1
        if (t > 0) {
            int iters = 0;
            while (true) {
                int f = __hip_atomic_load(&flags[lane], __ATOMIC_RELAXED,
                                          __HIP_MEMORY_SCOPE_AGENT);
                if (__all(f >= t)) break;
                __builtin_amdgcn_s_sleep(2);
                if (++iters > (1 << 24)) break;   // safety valve
            }
            __threadfence();                      // acquire
        }

        // 3) gate matmul: A fragments straight from global (L2/L3-resident)
        f32x4 acc0 = {0.f, 0.f, 0.f, 0.f}, acc1 = {0.f, 0.f, 0.f, 0.f};
        if (t > 0) {
            const unsigned short* hrow =
                hs + (size_t)(t - 1) * (B_ * H_) + (size_t)arow * H_;
#pragma unroll
            for (int kc = 0; kc < 16; kc += 2) {
                bf16x8 a0 = *(const bf16x8*)(hrow + kc * 32 + quad * 8);
                bf16x8 a1 = *(const bf16x8*)(hrow + kc * 32 + 32 + quad * 8);
                acc0 = __builtin_amdgcn_mfma_f32_16x16x32_bf16(a0, wh[kc], acc0, 0, 0, 0);
                acc1 = __builtin_amdgcn_mfma_f32_16x16x32_bf16(a1, wh[kc + 1], acc1, 0, 0, 0);
            }
        }
#pragma unroll
        for (int kc = 0; kc < 8; kc += 2) {
            acc0 = __builtin_amdgcn_mfma_f32_16x16x32_bf16(xf[kc], wi[kc], acc0, 0, 0, 0);
            acc1 = __builtin_amdgcn_mfma_f32_16x16x32_bf16(xf[kc + 1], wi[kc + 1], acc1, 0, 0, 0);
        }
        f32x4 acc = acc0 + acc1;

        // 4) C-frag -> LDS (row = b, col = jl); conflict-free via pad 33
#pragma unroll
        for (int r = 0; r < 4; ++r)
            gates_lds[(mt * 16 + quad * 4 + r) * 33 + nt * 16 + l15] = acc[r];
        __syncthreads();   // B2: gates visible

        // 5) elementwise LSTM cell (b = lane, local k = w)
        {
            float gi = gates_lds[lane * 33 + 0 * 8 + w] + bias[0];
            float gf = gates_lds[lane * 33 + 1 * 8 + w] + bias[1];
            float gg = gates_lds[lane * 33 + 2 * 8 + w] + bias[2];
            float go = gates_lds[lane * 33 + 3 * 8 + w] + bias[3];
            float i_s = sigm(gi);
            float f_s = sigm(gf);
            float g_t = tanh_(gg);
            float o_s = sigm(go);
            c_state = f_s * c_state + i_s * g_t;
            float h_new = o_s * tanh_(c_state);
            hs[(size_t)t * (B_ * H_) + (size_t)lane * H_ + p * 8 + w] =
                __builtin_bit_cast(unsigned short, (__bf16)h_new);
        }
        __syncthreads();   // B3: all stores drained (vmcnt0), gates reads done
        if (tid == 0) {
            __threadfence();               // release hs[t] to L3
            atomicAdd(&flags[p], 1);       // flags[p] = t+1
        }
    }
}

// ---------------------------------------------------------------------------
// Output projection: out[b,t,c] = hs[t,b,:] @ W_fc[c,:] + b_fc[c]
// 512 wgs (one per t) x 512 threads (8 waves); wave = c-tile, W_fc frags
// stationary in VGPRs; A frags straight from global hs.
// ---------------------------------------------------------------------------
__global__ void __launch_bounds__(512, 2)
out_kernel(const unsigned short* __restrict__ hs, const float* __restrict__ W_fc,
           const float* __restrict__ b_fc, float* __restrict__ out)
{
    const int t    = blockIdx.x;
    const int tid  = threadIdx.x;
    const int w    = tid >> 6;      // c-tile 0..7
    const int lane = tid & 63;
    const int l15  = lane & 15;
    const int quad = lane >> 4;

    bf16x8 wf[16];
#pragma unroll
    for (int kc = 0; kc < 16; ++kc) {
        const float* sp = W_fc + (size_t)(w * 16 + l15) * H_ + kc * 32 + quad * 8;
        wf[kc] = cvt8(((const float4*)sp)[0], ((const float4*)sp)[1]);
    }

    f32x4 acc[4];
#pragma unroll
    for (int m = 0; m < 4; ++m) acc[m] = (f32x4){0.f, 0.f, 0.f, 0.f};

    const unsigned short* hsrow = hs + (size_t)t * (B_ * H_);
#pragma unroll
    for (int kc = 0; kc < 16; ++kc) {
#pragma unroll
        for (int m = 0; m < 4; ++m) {
            bf16x8 a = *(const bf16x8*)(hsrow + (size_t)(m * 16 + l15) * H_ +
                                        kc * 32 + quad * 8);
            acc[m] = __builtin_amdgcn_mfma_f32_16x16x32_bf16(a, wf[kc], acc[m], 0, 0, 0);
        }
    }

    const int c = w * 16 + l15;
    const float bias = b_fc[c];
#pragma unroll
    for (int m = 0; m < 4; ++m) {
#pragma unroll
        for (int r = 0; r < 4; ++r) {
            int b = m * 16 + quad * 4 + r;
            out[(size_t)b * (T_ * C_) + (size_t)t * C_ + c] = acc[m][r] + bias;
        }
    }
}

extern "C" void kernel_launch(void* const* d_in, const int* in_sizes, int n_in,
                              void* d_out, int out_size, void* d_ws, size_t ws_size,
                              hipStream_t stream)
{
    const float* x    = (const float*)d_in[0];
    const float* W_ih = (const float*)d_in[1];
    const float* W_hh = (const float*)d_in[2];
    const float* b_ih = (const float*)d_in[3];
    const float* b_hh = (const float*)d_in[4];
    const float* W_fc = (const float*)d_in[5];
    const float* b_fc = (const float*)d_in[6];
    float* out = (float*)d_out;

    unsigned short* hs = (unsigned short*)d_ws;
    int* flags = (int*)((char*)d_ws + HS_BYTES);

    // flags region is poisoned 0xAA before every replay -> must zero on-stream
    hipMemsetAsync(flags, 0, NWG * sizeof(int), stream);

    lstm_kernel<<<NWG, 512, 0, stream>>>(x, W_ih, W_hh, b_ih, b_hh, hs, flags);
    out_kernel<<<T_, 512, 0, stream>>>(hs, W_fc, b_fc, out);
}

// Round 2
// 7630.991 us; speedup vs baseline: 1.2241x; 1.2241x over previous
//
#include <hip/hip_runtime.h>

// Problem: B=64, T=512, I=256, H=512, C=128. LSTM forward (truncation is a
// forward no-op) + final linear projection. fp32 in/out; bf16 MFMA inside.
#define B_ 64
#define T_ 512
#define I_ 256
#define H_ 512
#define C_ 128
#define NWG 64                // one wg per 8 h-columns; 32 gate rows each
#define HS_ELEMS ((size_t)T_ * B_ * H_)          // bf16 h archive/broadcast
#define HS_BYTES (HS_ELEMS * 2)                  // 32 MB

typedef __bf16 bf16x8 __attribute__((ext_vector_type(8)));
typedef float f32x4 __attribute__((ext_vector_type(4)));
typedef unsigned long long u64x2 __attribute__((ext_vector_type(2)));

__device__ __forceinline__ bf16x8 cvt8(const float4 a, const float4 b) {
    bf16x8 r;
    r[0] = (__bf16)a.x; r[1] = (__bf16)a.y; r[2] = (__bf16)a.z; r[3] = (__bf16)a.w;
    r[4] = (__bf16)b.x; r[5] = (__bf16)b.y; r[6] = (__bf16)b.z; r[7] = (__bf16)b.w;
    return r;
}

__device__ __forceinline__ float sigm(float x) {
    return __frcp_rn(1.0f + __expf(-x));
}
__device__ __forceinline__ float tanh_(float x) {
    return 2.0f * sigm(2.0f * x) - 1.0f;
}

// ---------------------------------------------------------------------------
// Recurrent kernel: 64 wgs x 512 threads (8 waves). wg p owns h columns
// [8p, 8p+8). Weights stationary in VGPRs. Cross-wg h exchange goes straight
// through L3 (agent-scope relaxed atomic u64 ld/st = sc0 sc1, cache-bypass),
// so NO acquire buffer_inv / release wbl2-over-dirty-lines is ever needed and
// the per-XCD L2 stays warm for x. One release fetch_add per wg per step on
// cnt[t]; consumers poll that single address (wave-coalesced same-addr load).
// ---------------------------------------------------------------------------
__global__ void __launch_bounds__(512, 2)
lstm_kernel(const float* __restrict__ x, const float* __restrict__ W_ih,
            const float* __restrict__ W_hh, const float* __restrict__ b_ih,
            const float* __restrict__ b_hh, unsigned short* __restrict__ hs,
            int* __restrict__ cnt)
{
    const int p    = blockIdx.x;          // 0..63
    const int tid  = threadIdx.x;
    const int w    = tid >> 6;            // wave 0..7
    const int lane = tid & 63;
    const int l15  = lane & 15;
    const int quad = lane >> 4;
    const int mt   = w >> 1;              // b-tile 0..3
    const int nt   = w & 1;               // gate-col tile 0..1
    const int arow = mt * 16 + l15;       // A-operand row (batch index b)

    __shared__ float gates_lds[64 * 33];          // [b][jl], pad 33
    __shared__ unsigned short h_tile[64 * 8];     // [b][w] gathered h (bf16)

    // ---- stationary weight fragments (B operand: B[k][n], n = lane&15) ----
    const int jl = nt * 16 + l15;                         // 0..31 within slice
    const int J  = (jl >> 3) * H_ + p * 8 + (jl & 7);     // global gate row
    bf16x8 wh[16], wi[8];
#pragma unroll
    for (int kc = 0; kc < 16; ++kc) {
        const float* sp = W_hh + (size_t)J * H_ + kc * 32 + quad * 8;
        wh[kc] = cvt8(((const float4*)sp)[0], ((const float4*)sp)[1]);
    }
#pragma unroll
    for (int kc = 0; kc < 8; ++kc) {
        const float* sp = W_ih + (size_t)J * I_ + kc * 32 + quad * 8;
        wi[kc] = cvt8(((const float4*)sp)[0], ((const float4*)sp)[1]);
    }

    // ---- per-thread elementwise identity: b = lane, local col k = w ----
    float bias[4];
#pragma unroll
    for (int g = 0; g < 4; ++g) {
        int j2 = g * H_ + p * 8 + w;
        bias[g] = b_ih[j2] + b_hh[j2];
    }
    float c_state = 0.0f;

    for (int t = 0; t < T_; ++t) {
        // 1) prefetch + convert this step's x fragments (L2-cached, read-only)
        bf16x8 xf[8];
#pragma unroll
        for (int kc = 0; kc < 8; ++kc) {
            const float* xp = x + ((size_t)arow * T_ + t) * I_ + kc * 32 + quad * 8;
            xf[kc] = cvt8(((const float4*)xp)[0], ((const float4*)xp)[1]);
        }

        f32x4 acc0 = {0.f, 0.f, 0.f, 0.f}, acc1 = {0.f, 0.f, 0.f, 0.f};

        if (t > 0) {
            // 2) wait for all 64 producers to finish step t-1 (single address,
            //    wave-coalesced same-addr relaxed atomic load)
            int iters = 0;
            while (__hip_atomic_load(&cnt[t - 1], __ATOMIC_RELAXED,
                                     __HIP_MEMORY_SCOPE_AGENT) < NWG) {
                __builtin_amdgcn_s_sleep(1);
                if (++iters > (1 << 22)) break;   // safety valve
            }

            // 3) h A-fragments straight from L3 (agent atomic u64 = sc1 loads)
            const unsigned long long* hrow = (const unsigned long long*)
                (hs + (size_t)(t - 1) * (B_ * H_) + (size_t)arow * H_);
#pragma unroll
            for (int kc = 0; kc < 16; kc += 2) {
                u64x2 ua, ub;
                ua.x = __hip_atomic_load(hrow + kc * 8 + quad * 2,
                                         __ATOMIC_RELAXED, __HIP_MEMORY_SCOPE_AGENT);
                ua.y = __hip_atomic_load(hrow + kc * 8 + quad * 2 + 1,
                                         __ATOMIC_RELAXED, __HIP_MEMORY_SCOPE_AGENT);
                ub.x = __hip_atomic_load(hrow + (kc + 1) * 8 + quad * 2,
                                         __ATOMIC_RELAXED, __HIP_MEMORY_SCOPE_AGENT);
                ub.y = __hip_atomic_load(hrow + (kc + 1) * 8 + quad * 2 + 1,
                                         __ATOMIC_RELAXED, __HIP_MEMORY_SCOPE_AGENT);
                bf16x8 a0 = __builtin_bit_cast(bf16x8, ua);
                bf16x8 a1 = __builtin_bit_cast(bf16x8, ub);
                acc0 = __builtin_amdgcn_mfma_f32_16x16x32_bf16(a0, wh[kc], acc0, 0, 0, 0);
                acc1 = __builtin_amdgcn_mfma_f32_16x16x32_bf16(a1, wh[kc + 1], acc1, 0, 0, 0);
            }
        }

        // 4) x contribution
#pragma unroll
        for (int kc = 0; kc < 8; kc += 2) {
            acc0 = __builtin_amdgcn_mfma_f32_16x16x32_bf16(xf[kc], wi[kc], acc0, 0, 0, 0);
            acc1 = __builtin_amdgcn_mfma_f32_16x16x32_bf16(xf[kc + 1], wi[kc + 1], acc1, 0, 0, 0);
        }
        f32x4 acc = acc0 + acc1;

        // 5) C-frag -> LDS (row = b, col = jl); pad 33 -> conflict-free
#pragma unroll
        for (int r = 0; r < 4; ++r)
            gates_lds[(mt * 16 + quad * 4 + r) * 33 + nt * 16 + l15] = acc[r];
        __syncthreads();   // B1: gates visible

        // 6) elementwise LSTM cell (b = lane, local col k = w); h -> LDS tile
        {
            float gi = gates_lds[lane * 33 + 0 * 8 + w] + bias[0];
            float gf = gates_lds[lane * 33 + 1 * 8 + w] + bias[1];
            float gg = gates_lds[lane * 33 + 2 * 8 + w] + bias[2];
            float go = gates_lds[lane * 33 + 3 * 8 + w] + bias[3];
            float i_s = sigm(gi);
            float f_s = sigm(gf);
            float g_t = tanh_(gg);
            float o_s = sigm(go);
            c_state = f_s * c_state + i_s * g_t;
            float h_new = o_s * tanh_(c_state);
            h_tile[lane * 8 + w] = __builtin_bit_cast(unsigned short, (__bf16)h_new);
        }
        __syncthreads();   // B2: h_tile complete, gates reads done

        // 7) wave 0 alone: gather 16B/row from LDS, push to L3 (sc1 stores),
        //    then ONE release fetch_add on cnt[t]. Other waves proceed to t+1.
        if (w == 0) {
            u64x2 v = *(const u64x2*)&h_tile[lane * 8];
            unsigned long long* dst = (unsigned long long*)
                (hs + (size_t)t * (B_ * H_) + (size_t)lane * H_ + p * 8);
            __hip_atomic_store(dst,     v.x, __ATOMIC_RELAXED, __HIP_MEMORY_SCOPE_AGENT);
            __hip_atomic_store(dst + 1, v.y, __ATOMIC_RELAXED, __HIP_MEMORY_SCOPE_AGENT);
            if (lane == 0)
                __hip_atomic_fetch_add(&cnt[t], 1, __ATOMIC_RELEASE,
                                       __HIP_MEMORY_SCOPE_AGENT);
        }
    }
}

// ---------------------------------------------------------------------------
// Output projection: out[b,t,c] = hs[t,b,:] @ W_fc[c,:] + b_fc[c]
// 512 wgs (one per t) x 512 threads; W_fc frags stationary in VGPRs.
// ---------------------------------------------------------------------------
__global__ void __launch_bounds__(512, 2)
out_kernel(const unsigned short* __restrict__ hs, const float* __restrict__ W_fc,
           const float* __restrict__ b_fc, float* __restrict__ out)
{
    const int t    = blockIdx.x;
    const int tid  = threadIdx.x;
    const int w    = tid >> 6;      // c-tile 0..7
    const int lane = tid & 63;
    const int l15  = lane & 15;
    const int quad = lane >> 4;

    bf16x8 wf[16];
#pragma unroll
    for (int kc = 0; kc < 16; ++kc) {
        const float* sp = W_fc + (size_t)(w * 16 + l15) * H_ + kc * 32 + quad * 8;
        wf[kc] = cvt8(((const float4*)sp)[0], ((const float4*)sp)[1]);
    }

    f32x4 acc[4];
#pragma unroll
    for (int m = 0; m < 4; ++m) acc[m] = (f32x4){0.f, 0.f, 0.f, 0.f};

    const unsigned short* hsrow = hs + (size_t)t * (B_ * H_);
#pragma unroll
    for (int kc = 0; kc < 16; ++kc) {
#pragma unroll
        for (int m = 0; m < 4; ++m) {
            bf16x8 a = *(const bf16x8*)(hsrow + (size_t)(m * 16 + l15) * H_ +
                                        kc * 32 + quad * 8);
            acc[m] = __builtin_amdgcn_mfma_f32_16x16x32_bf16(a, wf[kc], acc[m], 0, 0, 0);
        }
    }

    const int c = w * 16 + l15;
    const float bias = b_fc[c];
#pragma unroll
    for (int m = 0; m < 4; ++m) {
#pragma unroll
        for (int r = 0; r < 4; ++r) {
            int b = m * 16 + quad * 4 + r;
            out[(size_t)b * (T_ * C_) + (size_t)t * C_ + c] = acc[m][r] + bias;
        }
    }
}

extern "C" void kernel_launch(void* const* d_in, const int* in_sizes, int n_in,
                              void* d_out, int out_size, void* d_ws, size_t ws_size,
                              hipStream_t stream)
{
    const float* x    = (const float*)d_in[0];
    const float* W_ih = (const float*)d_in[1];
    const float* W_hh = (const float*)d_in[2];
    const float* b_ih = (const float*)d_in[3];
    const float* b_hh = (const float*)d_in[4];
    const float* W_fc = (const float*)d_in[5];
    const float* b_fc = (const float*)d_in[6];
    float* out = (float*)d_out;

    unsigned short* hs = (unsigned short*)d_ws;
    int* cnt = (int*)((char*)d_ws + HS_BYTES);

    // cnt region is poisoned 0xAA before every replay -> must zero on-stream
    hipMemsetAsync(cnt, 0, T_ * sizeof(int), stream);

    lstm_kernel<<<NWG, 512, 0, stream>>>(x, W_ih, W_hh, b_ih, b_hh, hs, cnt);
    out_kernel<<<T_, 512, 0, stream>>>(hs, W_fc, b_fc, out);
}

// Round 3
// 6177.766 us; speedup vs baseline: 1.5121x; 1.2352x over previous
//
#include <hip/hip_runtime.h>

// Problem: B=64, T=512, I=256, H=512, C=128. LSTM forward (truncation is a
// forward no-op) + final linear projection. fp32 in/out; bf16 MFMA inside.
#define B_ 64
#define T_ 512
#define I_ 256
#define H_ 512
#define C_ 128
#define NWG 64                // one wg per 8 h-columns; 32 gate rows each
#define HS_ELEMS ((size_t)T_ * B_ * H_)          // bf16 h archive/broadcast
#define HS_BYTES (HS_ELEMS * 2)                  // 32 MB

typedef __bf16 bf16x8 __attribute__((ext_vector_type(8)));
typedef float f32x4 __attribute__((ext_vector_type(4)));
typedef unsigned long long u64x2 __attribute__((ext_vector_type(2)));

__device__ __forceinline__ bf16x8 cvt8(const float4 a, const float4 b) {
    bf16x8 r;
    r[0] = (__bf16)a.x; r[1] = (__bf16)a.y; r[2] = (__bf16)a.z; r[3] = (__bf16)a.w;
    r[4] = (__bf16)b.x; r[5] = (__bf16)b.y; r[6] = (__bf16)b.z; r[7] = (__bf16)b.w;
    return r;
}

__device__ __forceinline__ float sigm(float x) {
    return __frcp_rn(1.0f + __expf(-x));
}
__device__ __forceinline__ float tanh_(float x) {
    return 2.0f * sigm(2.0f * x) - 1.0f;
}

// ---------------------------------------------------------------------------
// Recurrent kernel: 64 wgs x 512 threads (8 waves). wg p owns h columns
// [8p, 8p+8). Weights stationary in VGPRs.
//
// Barrier design (the whole game here):
//   - h exchange: agent-scope relaxed atomic u64 st/ld = sc0 sc1, i.e.
//     write-through/read-through to L3. Never dirty in any L2 -> no
//     buffer_wbl2 / buffer_inv needed anywhere.
//   - release: after wave0's h stores, a raw `s_waitcnt vmcnt(0)` (stores
//     ACKed at coherence point) then ONE plain relaxed store to this wg's
//     own flag word flag[t][p]. No RMW -> no L3 atomic-unit serialization,
//     no compiler-emitted wbl2.
//   - acquire side: each wave polls with ONE coalesced load flag[t-1][lane]
//     + __all ballot. 64 distinct words; reads don't contend with a hot
//     RMW address. h loads are themselves sc1 reads, so no inv needed.
// ---------------------------------------------------------------------------
__global__ void __launch_bounds__(512, 2)
lstm_kernel(const float* __restrict__ x, const float* __restrict__ W_ih,
            const float* __restrict__ W_hh, const float* __restrict__ b_ih,
            const float* __restrict__ b_hh, unsigned short* __restrict__ hs,
            int* __restrict__ flags)
{
    const int p    = blockIdx.x;          // 0..63
    const int tid  = threadIdx.x;
    const int w    = tid >> 6;            // wave 0..7
    const int lane = tid & 63;
    const int l15  = lane & 15;
    const int quad = lane >> 4;
    const int mt   = w >> 1;              // b-tile 0..3
    const int nt   = w & 1;               // gate-col tile 0..1
    const int arow = mt * 16 + l15;       // A-operand row (batch index b)

    __shared__ float gates_lds[64 * 33];          // [b][jl], pad 33
    __shared__ unsigned short h_tile[64 * 8];     // [b][w] gathered h (bf16)

    // ---- stationary weight fragments (B operand: B[k][n], n = lane&15) ----
    const int jl = nt * 16 + l15;                         // 0..31 within slice
    const int J  = (jl >> 3) * H_ + p * 8 + (jl & 7);     // global gate row
    bf16x8 wh[16], wi[8];
#pragma unroll
    for (int kc = 0; kc < 16; ++kc) {
        const float* sp = W_hh + (size_t)J * H_ + kc * 32 + quad * 8;
        wh[kc] = cvt8(((const float4*)sp)[0], ((const float4*)sp)[1]);
    }
#pragma unroll
    for (int kc = 0; kc < 8; ++kc) {
        const float* sp = W_ih + (size_t)J * I_ + kc * 32 + quad * 8;
        wi[kc] = cvt8(((const float4*)sp)[0], ((const float4*)sp)[1]);
    }

    // ---- per-thread elementwise identity: b = lane, local col k = w ----
    float bias[4];
#pragma unroll
    for (int g = 0; g < 4; ++g) {
        int j2 = g * H_ + p * 8 + w;
        bias[g] = b_ih[j2] + b_hh[j2];
    }
    float c_state = 0.0f;

    for (int t = 0; t < T_; ++t) {
        // 1) prefetch + convert this step's x fragments (L2-cached, read-only)
        bf16x8 xf[8];
#pragma unroll
        for (int kc = 0; kc < 8; ++kc) {
            const float* xp = x + ((size_t)arow * T_ + t) * I_ + kc * 32 + quad * 8;
            xf[kc] = cvt8(((const float4*)xp)[0], ((const float4*)xp)[1]);
        }

        f32x4 acc0 = {0.f, 0.f, 0.f, 0.f}, acc1 = {0.f, 0.f, 0.f, 0.f};

        if (t > 0) {
            // 2) wait: one coalesced load of the 64 per-wg flags + ballot
            const int* fl = flags + (size_t)(t - 1) * NWG;
            int iters = 0;
            while (true) {
                int f = __hip_atomic_load(&fl[lane], __ATOMIC_RELAXED,
                                          __HIP_MEMORY_SCOPE_AGENT);
                if (__all(f != 0)) break;
                __builtin_amdgcn_s_sleep(1);
                if (++iters > (1 << 22)) break;   // safety valve
            }

            // 3) h A-fragments straight from L3 (agent atomic u64 = sc1 loads)
            const unsigned long long* hrow = (const unsigned long long*)
                (hs + (size_t)(t - 1) * (B_ * H_) + (size_t)arow * H_);
#pragma unroll
            for (int kc = 0; kc < 16; kc += 2) {
                u64x2 ua, ub;
                ua.x = __hip_atomic_load(hrow + kc * 8 + quad * 2,
                                         __ATOMIC_RELAXED, __HIP_MEMORY_SCOPE_AGENT);
                ua.y = __hip_atomic_load(hrow + kc * 8 + quad * 2 + 1,
                                         __ATOMIC_RELAXED, __HIP_MEMORY_SCOPE_AGENT);
                ub.x = __hip_atomic_load(hrow + (kc + 1) * 8 + quad * 2,
                                         __ATOMIC_RELAXED, __HIP_MEMORY_SCOPE_AGENT);
                ub.y = __hip_atomic_load(hrow + (kc + 1) * 8 + quad * 2 + 1,
                                         __ATOMIC_RELAXED, __HIP_MEMORY_SCOPE_AGENT);
                bf16x8 a0 = __builtin_bit_cast(bf16x8, ua);
                bf16x8 a1 = __builtin_bit_cast(bf16x8, ub);
                acc0 = __builtin_amdgcn_mfma_f32_16x16x32_bf16(a0, wh[kc], acc0, 0, 0, 0);
                acc1 = __builtin_amdgcn_mfma_f32_16x16x32_bf16(a1, wh[kc + 1], acc1, 0, 0, 0);
            }
        }

        // 4) x contribution
#pragma unroll
        for (int kc = 0; kc < 8; kc += 2) {
            acc0 = __builtin_amdgcn_mfma_f32_16x16x32_bf16(xf[kc], wi[kc], acc0, 0, 0, 0);
            acc1 = __builtin_amdgcn_mfma_f32_16x16x32_bf16(xf[kc + 1], wi[kc + 1], acc1, 0, 0, 0);
        }
        f32x4 acc = acc0 + acc1;

        // 5) C-frag -> LDS (row = b, col = jl); pad 33 -> conflict-free
#pragma unroll
        for (int r = 0; r < 4; ++r)
            gates_lds[(mt * 16 + quad * 4 + r) * 33 + nt * 16 + l15] = acc[r];
        __syncthreads();   // B1: gates visible

        // 6) elementwise LSTM cell (b = lane, local col k = w); h -> LDS tile
        {
            float gi = gates_lds[lane * 33 + 0 * 8 + w] + bias[0];
            float gf = gates_lds[lane * 33 + 1 * 8 + w] + bias[1];
            float gg = gates_lds[lane * 33 + 2 * 8 + w] + bias[2];
            float go = gates_lds[lane * 33 + 3 * 8 + w] + bias[3];
            float i_s = sigm(gi);
            float f_s = sigm(gf);
            float g_t = tanh_(gg);
            float o_s = sigm(go);
            c_state = f_s * c_state + i_s * g_t;
            float h_new = o_s * tanh_(c_state);
            h_tile[lane * 8 + w] = __builtin_bit_cast(unsigned short, (__bf16)h_new);
        }
        __syncthreads();   // B2: h_tile complete, gates reads done

        // 7) wave 0: gather 16B/row from LDS, push to L3 (sc1 stores), drain
        //    with raw vmcnt(0), then ONE plain flag store. No RMW, no wbl2.
        if (w == 0) {
            u64x2 v = *(const u64x2*)&h_tile[lane * 8];
            unsigned long long* dst = (unsigned long long*)
                (hs + (size_t)t * (B_ * H_) + (size_t)lane * H_ + p * 8);
            __hip_atomic_store(dst,     v.x, __ATOMIC_RELAXED, __HIP_MEMORY_SCOPE_AGENT);
            __hip_atomic_store(dst + 1, v.y, __ATOMIC_RELAXED, __HIP_MEMORY_SCOPE_AGENT);
            asm volatile("s_waitcnt vmcnt(0)" ::: "memory");
            if (lane == 0)
                __hip_atomic_store(&flags[(size_t)t * NWG + p], 1,
                                   __ATOMIC_RELAXED, __HIP_MEMORY_SCOPE_AGENT);
        }
    }
}

// ---------------------------------------------------------------------------
// Output projection: out[b,t,c] = hs[t,b,:] @ W_fc[c,:] + b_fc[c]
// 512 wgs (one per t) x 512 threads; W_fc frags stationary in VGPRs.
// ---------------------------------------------------------------------------
__global__ void __launch_bounds__(512, 2)
out_kernel(const unsigned short* __restrict__ hs, const float* __restrict__ W_fc,
           const float* __restrict__ b_fc, float* __restrict__ out)
{
    const int t    = blockIdx.x;
    const int tid  = threadIdx.x;
    const int w    = tid >> 6;      // c-tile 0..7
    const int lane = tid & 63;
    const int l15  = lane & 15;
    const int quad = lane >> 4;

    bf16x8 wf[16];
#pragma unroll
    for (int kc = 0; kc < 16; ++kc) {
        const float* sp = W_fc + (size_t)(w * 16 + l15) * H_ + kc * 32 + quad * 8;
        wf[kc] = cvt8(((const float4*)sp)[0], ((const float4*)sp)[1]);
    }

    f32x4 acc[4];
#pragma unroll
    for (int m = 0; m < 4; ++m) acc[m] = (f32x4){0.f, 0.f, 0.f, 0.f};

    const unsigned short* hsrow = hs + (size_t)t * (B_ * H_);
#pragma unroll
    for (int kc = 0; kc < 16; ++kc) {
#pragma unroll
        for (int m = 0; m < 4; ++m) {
            bf16x8 a = *(const bf16x8*)(hsrow + (size_t)(m * 16 + l15) * H_ +
                                        kc * 32 + quad * 8);
            acc[m] = __builtin_amdgcn_mfma_f32_16x16x32_bf16(a, wf[kc], acc[m], 0, 0, 0);
        }
    }

    const int c = w * 16 + l15;
    const float bias = b_fc[c];
#pragma unroll
    for (int m = 0; m < 4; ++m) {
#pragma unroll
        for (int r = 0; r < 4; ++r) {
            int b = m * 16 + quad * 4 + r;
            out[(size_t)b * (T_ * C_) + (size_t)t * C_ + c] = acc[m][r] + bias;
        }
    }
}

extern "C" void kernel_launch(void* const* d_in, const int* in_sizes, int n_in,
                              void* d_out, int out_size, void* d_ws, size_t ws_size,
                              hipStream_t stream)
{
    const float* x    = (const float*)d_in[0];
    const float* W_ih = (const float*)d_in[1];
    const float* W_hh = (const float*)d_in[2];
    const float* b_ih = (const float*)d_in[3];
    const float* b_hh = (const float*)d_in[4];
    const float* W_fc = (const float*)d_in[5];
    const float* b_fc = (const float*)d_in[6];
    float* out = (float*)d_out;

    unsigned short* hs = (unsigned short*)d_ws;
    int* flags = (int*)((char*)d_ws + HS_BYTES);

    // flags region is poisoned 0xAA before every replay -> must zero on-stream
    hipMemsetAsync(flags, 0, (size_t)T_ * NWG * sizeof(int), stream);

    lstm_kernel<<<NWG, 512, 0, stream>>>(x, W_ih, W_hh, b_ih, b_hh, hs, flags);
    out_kernel<<<T_, 512, 0, stream>>>(hs, W_fc, b_fc, out);
}